// Round 8
// baseline (127.071 us; speedup 1.0000x reference)
//
#include <hip/hip_runtime.h>

typedef unsigned short u16;
typedef float f32x4 __attribute__((ext_vector_type(4)));
typedef __bf16 bf16x4 __attribute__((ext_vector_type(4)));
typedef __bf16 bf16x8 __attribute__((ext_vector_type(8)));

#define B_ 8
#define N_ 4096
#define C_ 256
#define NKV 256
// softmax scale folded into k: 1/sqrt(32) * log2(e)
#define CEXP 0.25506604f

__device__ inline u16 f2bf(float f) {
    union { float f; unsigned u; } v; v.f = f;
    unsigned r = v.u + 0x7FFF + ((v.u >> 16) & 1);
    return (u16)(r >> 16);
}

// async global->LDS, 16B per lane (dest must be wave-linear: base + lane*16)
__device__ inline void gload16(const void* g, void* l) {
    __builtin_amdgcn_global_load_lds(
        (const __attribute__((address_space(1))) void*)g,
        (__attribute__((address_space(3))) void*)l, 16, 0, 0);
}

// ---------------- prep (merged): x -> bf16 + im2col patches; weights -> bf16 ----------------
__global__ __launch_bounds__(256) void prep_all(
    const float* __restrict__ x, u16* __restrict__ xb, u16* __restrict__ patches,
    const float* __restrict__ qw, const float* __restrict__ kvw,
    const float* __restrict__ pw, const float* __restrict__ srw,
    u16* __restrict__ wqb, u16* __restrict__ wkv, u16* __restrict__ wp, u16* __restrict__ wsr)
{
    // x part: one float4 per thread over 8192x256 threads
    size_t base = ((size_t)blockIdx.x * 256 + threadIdx.x) * 4;
    float4 v = *(const float4*)(x + base);
    ushort4 o;
    o.x = f2bf(v.x); o.y = f2bf(v.y); o.z = f2bf(v.z); o.w = f2bf(v.w);
    *(ushort4*)(xb + base) = o;
    int c = (int)(base & 255);
    int n = (int)((base >> 8) & 4095);
    int b = (int)(base >> 20);
    int hh = n >> 6, ww = n & 63;
    int p = (hh >> 2) * 16 + (ww >> 2);
    int k = ((hh & 3) * 4 + (ww & 3)) * 256 + c;
    *(ushort4*)(patches + (size_t)(b * 256 + p) * 4096 + k) = o;

    // weight part (strided over the whole grid)
    int t = blockIdx.x * 256 + threadIdx.x;
    int stride = gridDim.x * 256;
    for (int i = t; i < 65536; i += stride) { wqb[i] = f2bf(qw[i]); wp[i] = f2bf(pw[i]); }
    for (int i = t; i < 131072; i += stride) wkv[i] = f2bf(kvw[i]);
    // wsr[o][(kh*4+kw)*256 + ci] = srw[o][ci][kh][kw]
    for (int i = t; i < 1048576; i += stride) {
        int oo = i >> 12, kk = i & 4095;
        int ci = kk & 255, khkw = kk >> 8;
        wsr[i] = f2bf(srw[(size_t)(oo * 256 + ci) * 16 + khkw]);
    }
}

// ---------------- staged 128x128 bf16 MFMA GEMM with global_load_lds (m97 pattern) ----------
// out = A[M,K] @ Bt[N,K]^T (+bias). LDS tiles [128][32] UNPADDED (global_load_lds requires
// linear lane->dest); fragment-read bank conflicts accepted (m97 pattern).
// OUTMODE: 0 = f32 out + bias, 1 = bf16 out + bias, 2 = f32 split-K partial (no bias)
// SCALEK: multiply cols < 256 by CEXP (softmax scale fold for the kv projection's k half)
template<int OUTMODE, bool SCALEK>
__global__ __launch_bounds__(256, 2) void gemm128(
    const u16* __restrict__ A, const u16* __restrict__ Bt,
    const float* __restrict__ bias, void* __restrict__ outp,
    int M, int Nn, int K, int kchunk)
{
    __shared__ __align__(16) u16 As[128 * 32];
    __shared__ __align__(16) u16 Bs[128 * 32];
    const int tid = threadIdx.x;
    const int bm = blockIdx.x, bn = blockIdx.y, bz = blockIdx.z;
    const int k0 = bz * kchunk;
    const int wid = tid >> 6, lane = tid & 63;
    const int wr = wid >> 1, wc = wid & 1;
    const int lrow = lane & 15, lkg = lane >> 4;

    f32x4 acc[4][4] = {};

    // staging: chunk c covers row c>>2, 16B-piece c&3 (linear in LDS)
    const int c1 = tid, c2 = tid + 256;
    const int r1 = c1 >> 2, cl1 = (c1 & 3) * 8;
    const int r2 = c2 >> 2, cl2 = (c2 & 3) * 8;
    const u16* aS1 = A  + (size_t)(bm * 128 + r1) * K + k0 + cl1;
    const u16* aS2 = A  + (size_t)(bm * 128 + r2) * K + k0 + cl2;
    const u16* bS1 = Bt + (size_t)(bn * 128 + r1) * K + k0 + cl1;
    const u16* bS2 = Bt + (size_t)(bn * 128 + r2) * K + k0 + cl2;
    u16* aD1 = As + c1 * 8;  u16* aD2 = As + c2 * 8;
    u16* bD1 = Bs + c1 * 8;  u16* bD2 = Bs + c2 * 8;

    for (int kk = 0; kk < kchunk; kk += 32) {
        gload16(aS1 + kk, aD1);
        gload16(aS2 + kk, aD2);
        gload16(bS1 + kk, bD1);
        gload16(bS2 + kk, bD2);
        __syncthreads();   // compiler drains vmcnt before s_barrier
        bf16x8 af[4], bff[4];
#pragma unroll
        for (int i = 0; i < 4; ++i) {
            af[i]  = *(const bf16x8*)(As + (wr * 64 + i * 16 + lrow) * 32 + lkg * 8);
            bff[i] = *(const bf16x8*)(Bs + (wc * 64 + i * 16 + lrow) * 32 + lkg * 8);
        }
#pragma unroll
        for (int i = 0; i < 4; ++i)
#pragma unroll
            for (int j = 0; j < 4; ++j)
                acc[i][j] = __builtin_amdgcn_mfma_f32_16x16x32_bf16(af[i], bff[j], acc[i][j], 0, 0, 0);
        __syncthreads();
    }

    const int row0 = bm * 128 + wr * 64;
    const int col0 = bn * 128 + wc * 64;
    if constexpr (OUTMODE == 2) {
        float* o = (float*)outp + (size_t)bz * M * Nn;
#pragma unroll
        for (int i = 0; i < 4; ++i)
#pragma unroll
            for (int j = 0; j < 4; ++j)
#pragma unroll
                for (int reg = 0; reg < 4; ++reg)
                    o[(size_t)(row0 + i * 16 + lkg * 4 + reg) * Nn + col0 + j * 16 + lrow] = acc[i][j][reg];
    } else {
#pragma unroll
        for (int j = 0; j < 4; ++j) {
            const int col = col0 + j * 16 + lrow;
            float bv = bias[col];
            float sc = 1.0f;
            if constexpr (SCALEK) { if (col < 256) sc = CEXP; }
#pragma unroll
            for (int i = 0; i < 4; ++i)
#pragma unroll
                for (int reg = 0; reg < 4; ++reg) {
                    const size_t idx = (size_t)(row0 + i * 16 + lkg * 4 + reg) * Nn + col;
                    const float val = (acc[i][j][reg] + bv) * sc;
                    if constexpr (OUTMODE == 1) ((u16*)outp)[idx] = f2bf(val);
                    else                        ((float*)outp)[idx] = val;
                }
        }
    }
}

// ---------------- LN over conv partial sums: xsr = LN(sum_z part + sr_b) -> bf16 ----------------
__global__ __launch_bounds__(256) void ln_kernel(
    const float* __restrict__ part, const float* __restrict__ srb,
    const float* __restrict__ g, const float* __restrict__ bb, u16* __restrict__ out)
{
    const int row = blockIdx.x, c = threadIdx.x;
    const size_t idx = (size_t)row * 256 + c;
    float v = srb[c];
#pragma unroll
    for (int z = 0; z < 8; ++z) v += part[idx + (size_t)z * 524288];
    float s = v;
#pragma unroll
    for (int m = 1; m < 64; m <<= 1) s += __shfl_xor(s, m);
    __shared__ float red[4];
    if ((c & 63) == 0) red[c >> 6] = s;
    __syncthreads();
    float tot = red[0] + red[1] + red[2] + red[3];
    float mu = tot * (1.0f / 256.0f);
    float d = v - mu;
    float s2 = d * d;
#pragma unroll
    for (int m = 1; m < 64; m <<= 1) s2 += __shfl_xor(s2, m);
    __syncthreads();
    if ((c & 63) == 0) red[c >> 6] = s2;
    __syncthreads();
    float var = (red[0] + red[1] + red[2] + red[3]) * (1.0f / 256.0f);
    out[idx] = f2bf(d * rsqrtf(var + 1e-5f) * g[c] + bb[c]);
}

// ---------------- fused attention v8: q-projection fused in, max-free softmax -------------
// Per block: (b, h, 64 q-rows). K[256][40] + V^T[32][264] in LDS (37.4 KB).
// q computed in-kernel: aq = mfma(A=wq rows, B=x rows) over K=256 gives, per lane,
// q[qrow=lrow][dh in {lkg*4+r, 16+lkg*4+r}] — exactly a B-fragment under the shared
// k-bijection slot(lkg,e) = (e<4 ? lkg*4+e : 16+lkg*4+e-4). QK^T then reads K as two
// ds_read_b64 at dh=lkg*4 / 16+lkg*4 (2 lanes/bank = free). Eliminates the q GEMM kernel
// and the 33.5 MB qbuf round-trip. k pre-scaled by CEXP in the kv GEMM; softmax is max-free
// (scores tiny: LN'd inputs x 0.02-scale weights; exp2 overflow needs |s|>120).
// Row-sums via ones-column MFMA land at lanes lrow==0, rows lkg*4+reg.
__global__ __launch_bounds__(256, 2) void attn_kernel(
    const u16* __restrict__ xb, const u16* __restrict__ wq, const float* __restrict__ qb,
    const u16* __restrict__ kvbuf, u16* __restrict__ obuf)
{
    __shared__ __align__(16) u16 Ks[256 * 40];   // 20480 B
    __shared__ __align__(16) u16 Vt[32 * 264];   // 16896 B  Vt[d][k]
    const int qt = blockIdx.x, h = blockIdx.y, b = blockIdx.z;
    const int tid = threadIdx.x;
    const int wid = tid >> 6, lane = tid & 63;
    const int lrow = lane & 15, lkg = lane >> 4;

    // stage K: thread t -> k-row t (4 x 16B), padded stride 40
    {
        const u16* ks = kvbuf + (size_t)(b * 256 + tid) * 512 + h * 32;
        u16* kd = Ks + tid * 40;
#pragma unroll
        for (int c = 0; c < 4; ++c)
            *(int4*)(kd + c * 8) = *(const int4*)(ks + c * 8);
    }
    // stage V^T: thread t reads v-row t, scatters 32 u16 (2 lanes/bank -> free)
    {
        const u16* vs = kvbuf + (size_t)(b * 256 + tid) * 512 + 256 + h * 32;
#pragma unroll
        for (int j = 0; j < 8; ++j) {
            ushort4 vv = *(const ushort4*)(vs + j * 4);
            Vt[(j * 4 + 0) * 264 + tid] = vv.x;
            Vt[(j * 4 + 1) * 264 + tid] = vv.y;
            Vt[(j * 4 + 2) * 264 + tid] = vv.z;
            Vt[(j * 4 + 3) * 264 + tid] = vv.w;
        }
    }

    // ---- fused q-projection (global-only; overlaps staging latency, before the barrier) ----
    // aq0: dh 0..15 (rows wq[h*32+lrow]); aq1: dh 16..31
    f32x4 aq0 = (f32x4){0.f, 0.f, 0.f, 0.f};
    f32x4 aq1 = (f32x4){0.f, 0.f, 0.f, 0.f};
    {
        const u16* xrow = xb + (size_t)(b * 4096 + qt * 64 + wid * 16 + lrow) * 256 + lkg * 8;
        const u16* wq0  = wq + (size_t)(h * 32 + lrow) * 256 + lkg * 8;
        const u16* wq1  = wq0 + 16 * 256;
#pragma unroll
        for (int ks = 0; ks < 8; ++ks) {
            bf16x8 xf = *(const bf16x8*)(xrow + ks * 32);
            aq0 = __builtin_amdgcn_mfma_f32_16x16x32_bf16(*(const bf16x8*)(wq0 + ks * 32), xf, aq0, 0, 0, 0);
            aq1 = __builtin_amdgcn_mfma_f32_16x16x32_bf16(*(const bf16x8*)(wq1 + ks * 32), xf, aq1, 0, 0, 0);
        }
    }
    // bias + pack to the bijection B-fragment
    const float4 qb0 = *(const float4*)(qb + h * 32 + lkg * 4);
    const float4 qb1 = *(const float4*)(qb + h * 32 + 16 + lkg * 4);
    bf16x8 qf;
    qf[0] = (__bf16)(aq0[0] + qb0.x); qf[1] = (__bf16)(aq0[1] + qb0.y);
    qf[2] = (__bf16)(aq0[2] + qb0.z); qf[3] = (__bf16)(aq0[3] + qb0.w);
    qf[4] = (__bf16)(aq1[0] + qb1.x); qf[5] = (__bf16)(aq1[1] + qb1.y);
    qf[6] = (__bf16)(aq1[2] + qb1.z); qf[7] = (__bf16)(aq1[3] + qb1.w);

    // ones B-fragment for the row-sum MFMA (col-of-tile 0 only)
    bf16x8 onesf = {};
    if (lrow == 0) {
#pragma unroll
        for (int e = 0; e < 8; ++e) onesf[e] = (__bf16)1.0f;
    }

    __syncthreads();

    // S^T = K @ Q^T; K A-frags read under the same bijection (two b64 per frag)
    f32x4 acc[16];
#pragma unroll
    for (int nf = 0; nf < 16; ++nf) acc[nf] = (f32x4){0.f, 0.f, 0.f, 0.f};
#pragma unroll
    for (int nf = 0; nf < 16; ++nf) {
        bf16x4 klo = *(const bf16x4*)(Ks + (nf * 16 + lrow) * 40 + lkg * 4);
        bf16x4 khi = *(const bf16x4*)(Ks + (nf * 16 + lrow) * 40 + 16 + lkg * 4);
        bf16x8 kfr = __builtin_shufflevector(klo, khi, 0, 1, 2, 3, 4, 5, 6, 7);
        acc[nf] = __builtin_amdgcn_mfma_f32_16x16x32_bf16(kfr, qf, acc[nf], 0, 0, 0);
    }

    // max-free softmax numerator: exp2 directly, fused bf16 pack
    bf16x8 pa8[8];
#pragma unroll
    for (int nf2 = 0; nf2 < 8; ++nf2) {
        bf16x8 pv;
#pragma unroll
        for (int half = 0; half < 2; ++half) {
#pragma unroll
            for (int r = 0; r < 4; ++r)
                pv[half * 4 + r] = (__bf16)exp2f(acc[2 * nf2 + half][r]);
        }
        pa8[nf2] = pv;
    }

    // O = P @ V via 16x16x32 with matching B-side bijection; o2 = row-sums via ones column
    f32x4 o0 = (f32x4){0.f, 0.f, 0.f, 0.f};
    f32x4 o1 = (f32x4){0.f, 0.f, 0.f, 0.f};
    f32x4 o2 = (f32x4){0.f, 0.f, 0.f, 0.f};
#pragma unroll
    for (int nf2 = 0; nf2 < 8; ++nf2) {
        bf16x4 lo0 = *(const bf16x4*)(Vt + lrow * 264 + nf2 * 32 + lkg * 4);
        bf16x4 hi0 = *(const bf16x4*)(Vt + lrow * 264 + nf2 * 32 + 16 + lkg * 4);
        bf16x4 lo1 = *(const bf16x4*)(Vt + (16 + lrow) * 264 + nf2 * 32 + lkg * 4);
        bf16x4 hi1 = *(const bf16x4*)(Vt + (16 + lrow) * 264 + nf2 * 32 + 16 + lkg * 4);
        bf16x8 v0 = __builtin_shufflevector(lo0, hi0, 0, 1, 2, 3, 4, 5, 6, 7);
        bf16x8 v1 = __builtin_shufflevector(lo1, hi1, 0, 1, 2, 3, 4, 5, 6, 7);
        o0 = __builtin_amdgcn_mfma_f32_16x16x32_bf16(pa8[nf2], v0, o0, 0, 0, 0);
        o1 = __builtin_amdgcn_mfma_f32_16x16x32_bf16(pa8[nf2], v1, o1, 0, 0, 0);
        o2 = __builtin_amdgcn_mfma_f32_16x16x32_bf16(pa8[nf2], onesf, o2, 0, 0, 0);
    }

    // 1/rowsum: sums live in lanes lrow==0 (rows lkg*4+r); broadcast within each lkg group
    float invq[4];
#pragma unroll
    for (int r = 0; r < 4; ++r)
        invq[r] = __shfl(__builtin_amdgcn_rcpf(o2[r]), lane & 48);

    const size_t obase = (size_t)(b * 4096 + qt * 64 + wid * 16);
#pragma unroll
    for (int r = 0; r < 4; ++r) {
        u16* op = obuf + (obase + lkg * 4 + r) * 256 + h * 32 + lrow;
        op[0]  = f2bf(o0[r] * invq[r]);
        op[16] = f2bf(o1[r] * invq[r]);
    }
}

extern "C" void kernel_launch(void* const* d_in, const int* in_sizes, int n_in,
                              void* d_out, int out_size, void* d_ws, size_t ws_size,
                              hipStream_t stream)
{
    (void)in_sizes; (void)n_in; (void)out_size; (void)ws_size;
    const float* x   = (const float*)d_in[0];
    const float* qw  = (const float*)d_in[3];
    const float* qb  = (const float*)d_in[4];
    const float* kvw = (const float*)d_in[5];
    const float* kvb = (const float*)d_in[6];
    const float* srw = (const float*)d_in[7];
    const float* srb = (const float*)d_in[8];
    const float* lng = (const float*)d_in[9];
    const float* lnb = (const float*)d_in[10];
    const float* pw  = (const float*)d_in[11];
    const float* pb  = (const float*)d_in[12];

    char* ws = (char*)d_ws;
    u16*   xb      = (u16*)(ws + 0);          // 16.78 MB  x as bf16 [32768][256]
    u16*   patches = (u16*)(ws + 16777216);   // 16.78 MB  im2col [2048][4096]; later reused as attn_out
    float* part    = (float*)(ws + 33554432); // 16.78 MB  conv split-K partials [8][2048][256]
    u16*   wsr     = (u16*)(ws + 50331648);   //  2.10 MB
    u16*   wqb     = (u16*)(ws + 52428800);
    u16*   wkvb    = (u16*)(ws + 52559872);
    u16*   wpb     = (u16*)(ws + 52822016);
    u16*   xsr     = (u16*)(ws + 52953088);   //  1.05 MB  LN output bf16 [2048][256]
    u16*   kvo     = (u16*)(ws + 54001664);   //  2.10 MB  kv bf16 [2048][512] (k pre-scaled)

    prep_all<<<8192, 256, 0, stream>>>(x, xb, patches, qw, kvw, pw, srw, wqb, wkvb, wpb, wsr);
    // conv as GEMM, split-K x8 -> f32 partials (256 blocks = full GPU)
    gemm128<2, false><<<dim3(16, 2, 8), 256, 0, stream>>>(patches, wsr, nullptr, part, 2048, 256, 4096, 512);
    ln_kernel<<<2048, 256, 0, stream>>>(part, srb, lng, lnb, xsr);
    gemm128<1, true ><<<dim3(16, 4, 1), 256, 0, stream>>>(xsr, wkvb, kvb, kvo, 2048, 512, 256, 256);
    attn_kernel<<<dim3(64, 8, 8), 256, 0, stream>>>(xb, wqb, qb, kvo, patches);
    gemm128<0, false><<<dim3(256, 2, 1), 256, 0, stream>>>(patches, wpb, pb, d_out, 32768, 256, 256, 256);
}

// Round 9
// 100.816 us; speedup vs baseline: 1.2604x; 1.2604x over previous
//
#include <hip/hip_runtime.h>

typedef unsigned short u16;
typedef float f32x4 __attribute__((ext_vector_type(4)));
typedef __bf16 bf16x4 __attribute__((ext_vector_type(4)));
typedef __bf16 bf16x8 __attribute__((ext_vector_type(8)));

#define B_ 8
#define N_ 4096
#define C_ 256
#define NKV 256
// softmax scale folded into k: 1/sqrt(32) * log2(e)
#define CEXP 0.25506604f

__device__ inline u16 f2bf(float f) {
    union { float f; unsigned u; } v; v.f = f;
    unsigned r = v.u + 0x7FFF + ((v.u >> 16) & 1);
    return (u16)(r >> 16);
}

// async global->LDS, 16B per lane (dest must be wave-linear: base + lane*16)
__device__ inline void gload16(const void* g, void* l) {
    __builtin_amdgcn_global_load_lds(
        (const __attribute__((address_space(1))) void*)g,
        (__attribute__((address_space(3))) void*)l, 16, 0, 0);
}

// ---------------- prep (merged): x -> bf16 xb; weights -> bf16 ----------------
__global__ __launch_bounds__(256) void prep_all(
    const float* __restrict__ x, u16* __restrict__ xb,
    const float* __restrict__ qw, const float* __restrict__ kvw,
    const float* __restrict__ pw, const float* __restrict__ srw,
    u16* __restrict__ wqb, u16* __restrict__ wkv, u16* __restrict__ wp, u16* __restrict__ wsr)
{
    // x part: one float4 per thread over 8192x256 threads (no im2col buffer:
    // the conv GEMM stages its A-tile straight from xb with im2col addressing)
    size_t base = ((size_t)blockIdx.x * 256 + threadIdx.x) * 4;
    float4 v = *(const float4*)(x + base);
    ushort4 o;
    o.x = f2bf(v.x); o.y = f2bf(v.y); o.z = f2bf(v.z); o.w = f2bf(v.w);
    *(ushort4*)(xb + base) = o;

    // weight part (strided over the whole grid)
    int t = blockIdx.x * 256 + threadIdx.x;
    int stride = gridDim.x * 256;
    for (int i = t; i < 65536; i += stride) { wqb[i] = f2bf(qw[i]); wp[i] = f2bf(pw[i]); }
    for (int i = t; i < 131072; i += stride) wkv[i] = f2bf(kvw[i]);
    // wsr[o][(kh*4+kw)*256 + ci] = srw[o][ci][kh][kw]
    for (int i = t; i < 1048576; i += stride) {
        int oo = i >> 12, kk = i & 4095;
        int ci = kk & 255, khkw = kk >> 8;
        wsr[i] = f2bf(srw[(size_t)(oo * 256 + ci) * 16 + khkw]);
    }
}

// ---------------- staged 128x128 bf16 MFMA GEMM with global_load_lds (m97 pattern) ----------
// out = A[M,K] @ Bt[N,K]^T (+bias). LDS tiles [128][32] UNPADDED (global_load_lds requires
// linear lane->dest); fragment-read bank conflicts accepted (m97 pattern).
// OUTMODE: 0 = f32 out + bias, 1 = bf16 out + bias, 2 = f32 split-K partial (no bias)
// SCALEK: multiply cols < 256 by CEXP (softmax scale fold for the kv projection's k half)
// IM2COL: A is xb [B*N][C]; logical A-row = b*256 + hp*16 + wp, k = (kh*4+kw)*256 + c.
//         Each 32-k chunk has fixed (kh,kw) (256%32==0); c stays contiguous -> same
//         coalescing; per-iteration address delta is wave-uniform scalar math.
template<int OUTMODE, bool SCALEK, bool IM2COL>
__global__ __launch_bounds__(256, 2) void gemm128(
    const u16* __restrict__ A, const u16* __restrict__ Bt,
    const float* __restrict__ bias, void* __restrict__ outp,
    int M, int Nn, int K, int kchunk)
{
    __shared__ __align__(16) u16 As[128 * 32];
    __shared__ __align__(16) u16 Bs[128 * 32];
    const int tid = threadIdx.x;
    const int bm = blockIdx.x, bn = blockIdx.y, bz = blockIdx.z;
    const int k0 = bz * kchunk;
    const int wid = tid >> 6, lane = tid & 63;
    const int wr = wid >> 1, wc = wid & 1;
    const int lrow = lane & 15, lkg = lane >> 4;

    f32x4 acc[4][4] = {};

    // staging: chunk c covers row c>>2, 16B-piece c&3 (linear in LDS)
    const int c1 = tid, c2 = tid + 256;
    const int r1 = c1 >> 2, cl1 = (c1 & 3) * 8;
    const int r2 = c2 >> 2, cl2 = (c2 & 3) * 8;
    const u16 *aS1, *aS2;
    if constexpr (IM2COL) {
        const int g1 = bm * 128 + r1, g2 = bm * 128 + r2;
        const int b1 = g1 >> 8, p1 = g1 & 255;
        const int b2 = g2 >> 8, p2 = g2 & 255;
        aS1 = A + ((size_t)(b1 * 4096 + (p1 >> 4) * 256 + (p1 & 15) * 4) * 256 + cl1);
        aS2 = A + ((size_t)(b2 * 4096 + (p2 >> 4) * 256 + (p2 & 15) * 4) * 256 + cl2);
    } else {
        aS1 = A + (size_t)(bm * 128 + r1) * K + k0 + cl1;
        aS2 = A + (size_t)(bm * 128 + r2) * K + k0 + cl2;
    }
    const u16* bS1 = Bt + (size_t)(bn * 128 + r1) * K + k0 + cl1;
    const u16* bS2 = Bt + (size_t)(bn * 128 + r2) * K + k0 + cl2;
    u16* aD1 = As + c1 * 8;  u16* aD2 = As + c2 * 8;
    u16* bD1 = Bs + c1 * 8;  u16* bD2 = Bs + c2 * 8;

    for (int kk = 0; kk < kchunk; kk += 32) {
        int aoff;
        if constexpr (IM2COL) {
            const int K0 = k0 + kk;
            const int khkw = K0 >> 8;
            aoff = ((khkw >> 2) * 64 + (khkw & 3)) * 256 + (K0 & 255);
        } else {
            aoff = kk;
        }
        gload16(aS1 + aoff, aD1);
        gload16(aS2 + aoff, aD2);
        gload16(bS1 + kk, bD1);
        gload16(bS2 + kk, bD2);
        __syncthreads();   // compiler drains vmcnt before s_barrier
        bf16x8 af[4], bff[4];
#pragma unroll
        for (int i = 0; i < 4; ++i) {
            af[i]  = *(const bf16x8*)(As + (wr * 64 + i * 16 + lrow) * 32 + lkg * 8);
            bff[i] = *(const bf16x8*)(Bs + (wc * 64 + i * 16 + lrow) * 32 + lkg * 8);
        }
#pragma unroll
        for (int i = 0; i < 4; ++i)
#pragma unroll
            for (int j = 0; j < 4; ++j)
                acc[i][j] = __builtin_amdgcn_mfma_f32_16x16x32_bf16(af[i], bff[j], acc[i][j], 0, 0, 0);
        __syncthreads();
    }

    const int row0 = bm * 128 + wr * 64;
    const int col0 = bn * 128 + wc * 64;
    if constexpr (OUTMODE == 2) {
        float* o = (float*)outp + (size_t)bz * M * Nn;
#pragma unroll
        for (int i = 0; i < 4; ++i)
#pragma unroll
            for (int j = 0; j < 4; ++j)
#pragma unroll
                for (int reg = 0; reg < 4; ++reg)
                    o[(size_t)(row0 + i * 16 + lkg * 4 + reg) * Nn + col0 + j * 16 + lrow] = acc[i][j][reg];
    } else {
#pragma unroll
        for (int j = 0; j < 4; ++j) {
            const int col = col0 + j * 16 + lrow;
            float bv = bias[col];
            float sc = 1.0f;
            if constexpr (SCALEK) { if (col < 256) sc = CEXP; }
#pragma unroll
            for (int i = 0; i < 4; ++i)
#pragma unroll
                for (int reg = 0; reg < 4; ++reg) {
                    const size_t idx = (size_t)(row0 + i * 16 + lkg * 4 + reg) * Nn + col;
                    const float val = (acc[i][j][reg] + bv) * sc;
                    if constexpr (OUTMODE == 1) ((u16*)outp)[idx] = f2bf(val);
                    else                        ((float*)outp)[idx] = val;
                }
        }
    }
}

// ---------------- LN over conv partial sums: xsr = LN(sum_z part + sr_b) -> bf16 ----------------
__global__ __launch_bounds__(256) void ln_kernel(
    const float* __restrict__ part, const float* __restrict__ srb,
    const float* __restrict__ g, const float* __restrict__ bb, u16* __restrict__ out)
{
    const int row = blockIdx.x, c = threadIdx.x;
    const size_t idx = (size_t)row * 256 + c;
    float v = srb[c];
#pragma unroll
    for (int z = 0; z < 8; ++z) v += part[idx + (size_t)z * 524288];
    float s = v;
#pragma unroll
    for (int m = 1; m < 64; m <<= 1) s += __shfl_xor(s, m);
    __shared__ float red[4];
    if ((c & 63) == 0) red[c >> 6] = s;
    __syncthreads();
    float tot = red[0] + red[1] + red[2] + red[3];
    float mu = tot * (1.0f / 256.0f);
    float d = v - mu;
    float s2 = d * d;
#pragma unroll
    for (int m = 1; m < 64; m <<= 1) s2 += __shfl_xor(s2, m);
    __syncthreads();
    if ((c & 63) == 0) red[c >> 6] = s2;
    __syncthreads();
    float var = (red[0] + red[1] + red[2] + red[3]) * (1.0f / 256.0f);
    out[idx] = f2bf(d * rsqrtf(var + 1e-5f) * g[c] + bb[c]);
}

// ---------------- fused attention (v7, proven): one 64-row q-tile per block ----------------
// Per block: (b, h, 64 q-rows); grid 4096 blocks. K[256][40] + V^T[32][264] in LDS (37.4 KB).
// Per-wave live state only {acc[16], pa8[8], qf} -> no spills. k pre-scaled by CEXP in the kv
// GEMM; softmax is max-free (scores tiny; exp2 overflow needs |s|>120). S^T layout = 16x16x32
// A-fragment under the shared k-bijection slot(lkg,e) = (e<4 ? lkg*4+e : 16+lkg*4+e-4).
// Row-sums via ones-column MFMA land at lanes lrow==0, rows lkg*4+reg.
__global__ __launch_bounds__(256, 2) void attn_kernel(
    const u16* __restrict__ qbuf, const u16* __restrict__ kvbuf, u16* __restrict__ obuf)
{
    __shared__ __align__(16) u16 Ks[256 * 40];   // 20480 B
    __shared__ __align__(16) u16 Vt[32 * 264];   // 16896 B  Vt[d][k]
    const int qt = blockIdx.x, h = blockIdx.y, b = blockIdx.z;
    const int tid = threadIdx.x;
    const int wid = tid >> 6, lane = tid & 63;
    const int lrow = lane & 15, lkg = lane >> 4;

    // stage K: thread t -> k-row t (4 x 16B), padded stride 40 (conflict-free frag reads)
    {
        const u16* ks = kvbuf + (size_t)(b * 256 + tid) * 512 + h * 32;
        u16* kd = Ks + tid * 40;
#pragma unroll
        for (int c = 0; c < 4; ++c)
            *(int4*)(kd + c * 8) = *(const int4*)(ks + c * 8);
    }
    // stage V^T: thread t reads v-row t, scatters 32 u16 (2 lanes/bank -> free)
    {
        const u16* vs = kvbuf + (size_t)(b * 256 + tid) * 512 + 256 + h * 32;
#pragma unroll
        for (int j = 0; j < 8; ++j) {
            ushort4 vv = *(const ushort4*)(vs + j * 4);
            Vt[(j * 4 + 0) * 264 + tid] = vv.x;
            Vt[(j * 4 + 1) * 264 + tid] = vv.y;
            Vt[(j * 4 + 2) * 264 + tid] = vv.z;
            Vt[(j * 4 + 3) * 264 + tid] = vv.w;
        }
    }

    // Q B-fragment straight from global (16B/lane)
    const int qcol = h * 32 + lkg * 8;
    bf16x8 qf = *(const bf16x8*)(qbuf +
        (size_t)(b * 4096 + qt * 64 + wid * 16 + lrow) * 256 + qcol);

    // ones B-fragment for the row-sum MFMA (col-of-tile 0 only)
    bf16x8 onesf = {};
    if (lrow == 0) {
#pragma unroll
        for (int e = 0; e < 8; ++e) onesf[e] = (__bf16)1.0f;
    }

    __syncthreads();

    // S^T = K @ Q^T (scores pre-scaled by CEXP via the kv GEMM)
    f32x4 acc[16];
#pragma unroll
    for (int nf = 0; nf < 16; ++nf) acc[nf] = (f32x4){0.f, 0.f, 0.f, 0.f};
#pragma unroll
    for (int nf = 0; nf < 16; ++nf) {
        bf16x8 kfr = *(const bf16x8*)(Ks + (nf * 16 + lrow) * 40 + lkg * 8);
        acc[nf] = __builtin_amdgcn_mfma_f32_16x16x32_bf16(kfr, qf, acc[nf], 0, 0, 0);
    }

    // max-free softmax numerator: exp2 directly, fused bf16 pack
    bf16x8 pa8[8];
#pragma unroll
    for (int nf2 = 0; nf2 < 8; ++nf2) {
        bf16x8 pv;
#pragma unroll
        for (int half = 0; half < 2; ++half) {
#pragma unroll
            for (int r = 0; r < 4; ++r)
                pv[half * 4 + r] = (__bf16)exp2f(acc[2 * nf2 + half][r]);
        }
        pa8[nf2] = pv;
    }

    // O = P @ V via 16x16x32 with matching B-side bijection; o2 = row-sums via ones column
    f32x4 o0 = (f32x4){0.f, 0.f, 0.f, 0.f};
    f32x4 o1 = (f32x4){0.f, 0.f, 0.f, 0.f};
    f32x4 o2 = (f32x4){0.f, 0.f, 0.f, 0.f};
#pragma unroll
    for (int nf2 = 0; nf2 < 8; ++nf2) {
        bf16x4 lo0 = *(const bf16x4*)(Vt + lrow * 264 + nf2 * 32 + lkg * 4);
        bf16x4 hi0 = *(const bf16x4*)(Vt + lrow * 264 + nf2 * 32 + 16 + lkg * 4);
        bf16x4 lo1 = *(const bf16x4*)(Vt + (16 + lrow) * 264 + nf2 * 32 + lkg * 4);
        bf16x4 hi1 = *(const bf16x4*)(Vt + (16 + lrow) * 264 + nf2 * 32 + 16 + lkg * 4);
        bf16x8 v0 = __builtin_shufflevector(lo0, hi0, 0, 1, 2, 3, 4, 5, 6, 7);
        bf16x8 v1 = __builtin_shufflevector(lo1, hi1, 0, 1, 2, 3, 4, 5, 6, 7);
        o0 = __builtin_amdgcn_mfma_f32_16x16x32_bf16(pa8[nf2], v0, o0, 0, 0, 0);
        o1 = __builtin_amdgcn_mfma_f32_16x16x32_bf16(pa8[nf2], v1, o1, 0, 0, 0);
        o2 = __builtin_amdgcn_mfma_f32_16x16x32_bf16(pa8[nf2], onesf, o2, 0, 0, 0);
    }

    // 1/rowsum: sums live in lanes lrow==0 (rows lkg*4+r); broadcast within each lkg group
    float invq[4];
#pragma unroll
    for (int r = 0; r < 4; ++r)
        invq[r] = __shfl(__builtin_amdgcn_rcpf(o2[r]), lane & 48);

    const size_t obase = (size_t)(b * 4096 + qt * 64 + wid * 16);
#pragma unroll
    for (int r = 0; r < 4; ++r) {
        u16* op = obuf + (obase + lkg * 4 + r) * 256 + h * 32 + lrow;
        op[0]  = f2bf(o0[r] * invq[r]);
        op[16] = f2bf(o1[r] * invq[r]);
    }
}

extern "C" void kernel_launch(void* const* d_in, const int* in_sizes, int n_in,
                              void* d_out, int out_size, void* d_ws, size_t ws_size,
                              hipStream_t stream)
{
    (void)in_sizes; (void)n_in; (void)out_size; (void)ws_size;
    const float* x   = (const float*)d_in[0];
    const float* qw  = (const float*)d_in[3];
    const float* qb  = (const float*)d_in[4];
    const float* kvw = (const float*)d_in[5];
    const float* kvb = (const float*)d_in[6];
    const float* srw = (const float*)d_in[7];
    const float* srb = (const float*)d_in[8];
    const float* lng = (const float*)d_in[9];
    const float* lnb = (const float*)d_in[10];
    const float* pw  = (const float*)d_in[11];
    const float* pb  = (const float*)d_in[12];

    char* ws = (char*)d_ws;
    u16*   xb      = (u16*)(ws + 0);          // 16.78 MB  x as bf16 [32768][256]
    u16*   att     = (u16*)(ws + 16777216);   // 16.78 MB  attention output bf16 [32768][256]
    float* part    = (float*)(ws + 33554432); // 16.78 MB  conv split-K partials [8][2048][256]
    u16*   wsr     = (u16*)(ws + 50331648);   //  2.10 MB
    u16*   wqb     = (u16*)(ws + 52428800);
    u16*   wkvb    = (u16*)(ws + 52559872);
    u16*   wpb     = (u16*)(ws + 52822016);
    u16*   xsr     = (u16*)(ws + 52953088);   //  1.05 MB  LN output bf16 [2048][256]
    u16*   kvo     = (u16*)(ws + 54001664);   //  2.10 MB  kv bf16 [2048][512] (k pre-scaled)
    u16*   qbuf    = (u16*)d_out;             // q bf16 [32768][256] in d_out scratch (overwritten by proj)

    prep_all<<<8192, 256, 0, stream>>>(x, xb, qw, kvw, pw, srw, wqb, wkvb, wpb, wsr);
    // conv as GEMM with im2col-on-the-fly A staging, split-K x8 (256 blocks = full GPU)
    gemm128<2, false, true ><<<dim3(16, 2, 8), 256, 0, stream>>>(xb, wsr, nullptr, part, 2048, 256, 4096, 512);
    ln_kernel<<<2048, 256, 0, stream>>>(part, srb, lng, lnb, xsr);
    gemm128<1, true,  false><<<dim3(16, 4, 1), 256, 0, stream>>>(xsr, wkvb, kvb, kvo, 2048, 512, 256, 256);
    gemm128<1, false, false><<<dim3(256, 2, 1), 256, 0, stream>>>(xb, wqb, qb, qbuf, 32768, 256, 256, 256);
    attn_kernel<<<dim3(64, 8, 8), 256, 0, stream>>>(qbuf, kvo, att);
    gemm128<0, false, false><<<dim3(256, 2, 1), 256, 0, stream>>>(att, wpb, pb, d_out, 32768, 256, 256, 256);
}

// Round 10
// 95.217 us; speedup vs baseline: 1.3345x; 1.0588x over previous
//
#include <hip/hip_runtime.h>

typedef unsigned short u16;
typedef float f32x4 __attribute__((ext_vector_type(4)));
typedef __bf16 bf16x4 __attribute__((ext_vector_type(4)));
typedef __bf16 bf16x8 __attribute__((ext_vector_type(8)));

#define B_ 8
#define N_ 4096
#define C_ 256
#define NKV 256
// softmax scale folded into k: 1/sqrt(32) * log2(e)
#define CEXP 0.25506604f

__device__ inline u16 f2bf(float f) {
    union { float f; unsigned u; } v; v.f = f;
    unsigned r = v.u + 0x7FFF + ((v.u >> 16) & 1);
    return (u16)(r >> 16);
}

// async global->LDS, 16B per lane (dest must be wave-linear: base + lane*16)
__device__ inline void gload16(const void* g, void* l) {
    __builtin_amdgcn_global_load_lds(
        (const __attribute__((address_space(1))) void*)g,
        (__attribute__((address_space(3))) void*)l, 16, 0, 0);
}

// ---------------- prep (merged): x -> bf16 xb; weights -> bf16 ----------------
__global__ __launch_bounds__(256) void prep_all(
    const float* __restrict__ x, u16* __restrict__ xb,
    const float* __restrict__ qw, const float* __restrict__ kvw,
    const float* __restrict__ pw, const float* __restrict__ srw,
    u16* __restrict__ wqb, u16* __restrict__ wkv, u16* __restrict__ wp, u16* __restrict__ wsr)
{
    // x part: one float4 per thread over 8192x256 threads (no im2col buffer:
    // the conv GEMM stages its A-tile straight from xb with im2col addressing)
    size_t base = ((size_t)blockIdx.x * 256 + threadIdx.x) * 4;
    float4 v = *(const float4*)(x + base);
    ushort4 o;
    o.x = f2bf(v.x); o.y = f2bf(v.y); o.z = f2bf(v.z); o.w = f2bf(v.w);
    *(ushort4*)(xb + base) = o;

    // weight part (strided over the whole grid)
    int t = blockIdx.x * 256 + threadIdx.x;
    int stride = gridDim.x * 256;
    for (int i = t; i < 65536; i += stride) { wqb[i] = f2bf(qw[i]); wp[i] = f2bf(pw[i]); }
    for (int i = t; i < 131072; i += stride) wkv[i] = f2bf(kvw[i]);
    // wsr[o][(kh*4+kw)*256 + ci] = srw[o][ci][kh][kw]
    for (int i = t; i < 1048576; i += stride) {
        int oo = i >> 12, kk = i & 4095;
        int ci = kk & 255, khkw = kk >> 8;
        wsr[i] = f2bf(srw[(size_t)(oo * 256 + ci) * 16 + khkw]);
    }
}

// ---------------- 128x128 bf16 MFMA GEMM body with global_load_lds staging ----------------
// out = A[M,K] @ Bt[N,K]^T (+bias). LDS tiles [128][32] UNPADDED (global_load_lds requires
// linear lane->dest); fragment-read bank conflicts accepted (m97 pattern).
// OUTMODE: 0 = f32 out + bias, 1 = bf16 out + bias, 2 = f32 split-K partial (no bias)
// SCALEK: multiply cols < 256 by CEXP (softmax scale fold for the kv projection's k half)
// IM2COL: A is xb [B*N][C]; logical A-row = b*256 + hp*16 + wp, k = (kh*4+kw)*256 + c.
template<int OUTMODE, bool SCALEK, bool IM2COL>
__device__ __forceinline__ void gemm_body(
    u16* As, u16* Bs,
    const u16* __restrict__ A, const u16* __restrict__ Bt,
    const float* __restrict__ bias, void* __restrict__ outp,
    int M, int Nn, int K, int kchunk, int bm, int bn, int bz)
{
    const int tid = threadIdx.x;
    const int k0 = bz * kchunk;
    const int wid = tid >> 6, lane = tid & 63;
    const int wr = wid >> 1, wc = wid & 1;
    const int lrow = lane & 15, lkg = lane >> 4;

    f32x4 acc[4][4] = {};

    // staging: chunk c covers row c>>2, 16B-piece c&3 (linear in LDS)
    const int c1 = tid, c2 = tid + 256;
    const int r1 = c1 >> 2, cl1 = (c1 & 3) * 8;
    const int r2 = c2 >> 2, cl2 = (c2 & 3) * 8;
    const u16 *aS1, *aS2;
    if constexpr (IM2COL) {
        const int g1 = bm * 128 + r1, g2 = bm * 128 + r2;
        const int b1 = g1 >> 8, p1 = g1 & 255;
        const int b2 = g2 >> 8, p2 = g2 & 255;
        aS1 = A + ((size_t)(b1 * 4096 + (p1 >> 4) * 256 + (p1 & 15) * 4) * 256 + cl1);
        aS2 = A + ((size_t)(b2 * 4096 + (p2 >> 4) * 256 + (p2 & 15) * 4) * 256 + cl2);
    } else {
        aS1 = A + (size_t)(bm * 128 + r1) * K + k0 + cl1;
        aS2 = A + (size_t)(bm * 128 + r2) * K + k0 + cl2;
    }
    const u16* bS1 = Bt + (size_t)(bn * 128 + r1) * K + k0 + cl1;
    const u16* bS2 = Bt + (size_t)(bn * 128 + r2) * K + k0 + cl2;
    u16* aD1 = As + c1 * 8;  u16* aD2 = As + c2 * 8;
    u16* bD1 = Bs + c1 * 8;  u16* bD2 = Bs + c2 * 8;

    for (int kk = 0; kk < kchunk; kk += 32) {
        int aoff;
        if constexpr (IM2COL) {
            const int K0 = k0 + kk;
            const int khkw = K0 >> 8;
            aoff = ((khkw >> 2) * 64 + (khkw & 3)) * 256 + (K0 & 255);
        } else {
            aoff = kk;
        }
        gload16(aS1 + aoff, aD1);
        gload16(aS2 + aoff, aD2);
        gload16(bS1 + kk, bD1);
        gload16(bS2 + kk, bD2);
        __syncthreads();   // compiler drains vmcnt before s_barrier
        bf16x8 af[4], bff[4];
#pragma unroll
        for (int i = 0; i < 4; ++i) {
            af[i]  = *(const bf16x8*)(As + (wr * 64 + i * 16 + lrow) * 32 + lkg * 8);
            bff[i] = *(const bf16x8*)(Bs + (wc * 64 + i * 16 + lrow) * 32 + lkg * 8);
        }
#pragma unroll
        for (int i = 0; i < 4; ++i)
#pragma unroll
            for (int j = 0; j < 4; ++j)
                acc[i][j] = __builtin_amdgcn_mfma_f32_16x16x32_bf16(af[i], bff[j], acc[i][j], 0, 0, 0);
        __syncthreads();
    }

    const int row0 = bm * 128 + wr * 64;
    const int col0 = bn * 128 + wc * 64;
    if constexpr (OUTMODE == 2) {
        float* o = (float*)outp + (size_t)bz * M * Nn;
#pragma unroll
        for (int i = 0; i < 4; ++i)
#pragma unroll
            for (int j = 0; j < 4; ++j)
#pragma unroll
                for (int reg = 0; reg < 4; ++reg)
                    o[(size_t)(row0 + i * 16 + lkg * 4 + reg) * Nn + col0 + j * 16 + lrow] = acc[i][j][reg];
    } else {
#pragma unroll
        for (int j = 0; j < 4; ++j) {
            const int col = col0 + j * 16 + lrow;
            float bv = bias[col];
            float sc = 1.0f;
            if constexpr (SCALEK) { if (col < 256) sc = CEXP; }
#pragma unroll
            for (int i = 0; i < 4; ++i)
#pragma unroll
                for (int reg = 0; reg < 4; ++reg) {
                    const size_t idx = (size_t)(row0 + i * 16 + lkg * 4 + reg) * Nn + col;
                    const float val = (acc[i][j][reg] + bv) * sc;
                    if constexpr (OUTMODE == 1) ((u16*)outp)[idx] = f2bf(val);
                    else                        ((float*)outp)[idx] = val;
                }
        }
    }
}

// standalone GEMM wrapper (kv projection, output projection)
template<int OUTMODE, bool SCALEK, bool IM2COL>
__global__ __launch_bounds__(256, 2) void gemm128(
    const u16* __restrict__ A, const u16* __restrict__ Bt,
    const float* __restrict__ bias, void* __restrict__ outp,
    int M, int Nn, int K, int kchunk)
{
    __shared__ __align__(16) u16 As[128 * 32];
    __shared__ __align__(16) u16 Bs[128 * 32];
    gemm_body<OUTMODE, SCALEK, IM2COL>(As, Bs, A, Bt, bias, outp, M, Nn, K, kchunk,
                                       blockIdx.x, blockIdx.y, blockIdx.z);
}

// ---------------- fused launch: conv GEMM (split-K x4, im2col) + q projection -------------
// ids 0..127: conv (16 bm x 2 bn x 4 z, K=1024 each) — long poles dispatched first.
// ids 128..639: q proj (256 bm x 2 bn, K=256). Independent work fills remaining CUs.
__global__ __launch_bounds__(256, 2) void fused_convq(
    const u16* __restrict__ xb, const u16* __restrict__ wsr, float* __restrict__ part,
    const u16* __restrict__ wqb, const float* __restrict__ qb, u16* __restrict__ qbuf)
{
    __shared__ __align__(16) u16 As[128 * 32];
    __shared__ __align__(16) u16 Bs[128 * 32];
    const int id = blockIdx.x;
    if (id < 128) {
        const int z = id & 3, t = id >> 2;
        gemm_body<2, false, true>(As, Bs, xb, wsr, nullptr, part,
                                  2048, 256, 4096, 1024, t >> 1, t & 1, z);
    } else {
        const int qid = id - 128;
        gemm_body<1, false, false>(As, Bs, xb, wqb, qb, qbuf,
                                   32768, 256, 256, 256, qid >> 1, qid & 1, 0);
    }
}

// ---------------- LN over conv partial sums: xsr = LN(sum_z part + sr_b) -> bf16 ----------------
__global__ __launch_bounds__(256) void ln_kernel(
    const float* __restrict__ part, const float* __restrict__ srb,
    const float* __restrict__ g, const float* __restrict__ bb, u16* __restrict__ out)
{
    const int row = blockIdx.x, c = threadIdx.x;
    const size_t idx = (size_t)row * 256 + c;
    float v = srb[c];
#pragma unroll
    for (int z = 0; z < 4; ++z) v += part[idx + (size_t)z * 524288];
    float s = v;
#pragma unroll
    for (int m = 1; m < 64; m <<= 1) s += __shfl_xor(s, m);
    __shared__ float red[4];
    if ((c & 63) == 0) red[c >> 6] = s;
    __syncthreads();
    float tot = red[0] + red[1] + red[2] + red[3];
    float mu = tot * (1.0f / 256.0f);
    float d = v - mu;
    float s2 = d * d;
#pragma unroll
    for (int m = 1; m < 64; m <<= 1) s2 += __shfl_xor(s2, m);
    __syncthreads();
    if ((c & 63) == 0) red[c >> 6] = s2;
    __syncthreads();
    float var = (red[0] + red[1] + red[2] + red[3]) * (1.0f / 256.0f);
    out[idx] = f2bf(d * rsqrtf(var + 1e-5f) * g[c] + bb[c]);
}

// ---------------- fused attention (v7 structure; K staged via global_load_lds) ------------
// Per block: (b, h, 64 q-rows); grid 4096 blocks. K[256][32] linear (async staged) +
// V^T[32][264] in LDS (33.3 KB -> 4 blocks/CU). QK fragment reads eat a 4-way bank
// conflict (m136: 1.58x on a short read phase) in exchange for async K staging with no
// VGPR round-trip. k pre-scaled by CEXP in the kv GEMM; softmax is max-free (scores tiny).
// S^T layout = 16x16x32 A-fragment under the shared k-bijection
// slot(lkg,e) = (e<4 ? lkg*4+e : 16+lkg*4+e-4). Row-sums via ones-column MFMA.
__global__ __launch_bounds__(256, 2) void attn_kernel(
    const u16* __restrict__ qbuf, const u16* __restrict__ kvbuf, u16* __restrict__ obuf)
{
    __shared__ __align__(16) u16 Ks[256 * 32];   // 16384 B (linear: row r at r*32)
    __shared__ __align__(16) u16 Vt[32 * 264];   // 16896 B  Vt[d][k]
    const int qt = blockIdx.x, h = blockIdx.y, b = blockIdx.z;
    const int tid = threadIdx.x;
    const int wid = tid >> 6, lane = tid & 63;
    const int lrow = lane & 15, lkg = lane >> 4;

    // stage K via async global->LDS: call c (= wid*4+i) covers rows [c*16, c*16+16)
    {
        const int rsub = lane >> 2, piece = lane & 3;
#pragma unroll
        for (int i = 0; i < 4; ++i) {
            const int c = wid * 4 + i;
            const u16* src = kvbuf + (size_t)(b * 256 + c * 16 + rsub) * 512 + h * 32 + piece * 8;
            gload16(src, Ks + c * 512 + lane * 8);
        }
    }
    // stage V^T: thread t reads v-row t, scatters 32 u16 (2 lanes/bank -> free)
    {
        const u16* vs = kvbuf + (size_t)(b * 256 + tid) * 512 + 256 + h * 32;
#pragma unroll
        for (int j = 0; j < 8; ++j) {
            ushort4 vv = *(const ushort4*)(vs + j * 4);
            Vt[(j * 4 + 0) * 264 + tid] = vv.x;
            Vt[(j * 4 + 1) * 264 + tid] = vv.y;
            Vt[(j * 4 + 2) * 264 + tid] = vv.z;
            Vt[(j * 4 + 3) * 264 + tid] = vv.w;
        }
    }

    // Q B-fragment straight from global (16B/lane)
    const int qcol = h * 32 + lkg * 8;
    bf16x8 qf = *(const bf16x8*)(qbuf +
        (size_t)(b * 4096 + qt * 64 + wid * 16 + lrow) * 256 + qcol);

    // ones B-fragment for the row-sum MFMA (col-of-tile 0 only)
    bf16x8 onesf = {};
    if (lrow == 0) {
#pragma unroll
        for (int e = 0; e < 8; ++e) onesf[e] = (__bf16)1.0f;
    }

    __syncthreads();

    // S^T = K @ Q^T (scores pre-scaled by CEXP via the kv GEMM)
    f32x4 acc[16];
#pragma unroll
    for (int nf = 0; nf < 16; ++nf) acc[nf] = (f32x4){0.f, 0.f, 0.f, 0.f};
#pragma unroll
    for (int nf = 0; nf < 16; ++nf) {
        bf16x8 kfr = *(const bf16x8*)(Ks + (nf * 16 + lrow) * 32 + lkg * 8);
        acc[nf] = __builtin_amdgcn_mfma_f32_16x16x32_bf16(kfr, qf, acc[nf], 0, 0, 0);
    }

    // max-free softmax numerator: exp2 directly, fused bf16 pack
    bf16x8 pa8[8];
#pragma unroll
    for (int nf2 = 0; nf2 < 8; ++nf2) {
        bf16x8 pv;
#pragma unroll
        for (int half = 0; half < 2; ++half) {
#pragma unroll
            for (int r = 0; r < 4; ++r)
                pv[half * 4 + r] = (__bf16)exp2f(acc[2 * nf2 + half][r]);
        }
        pa8[nf2] = pv;
    }

    // O = P @ V via 16x16x32 with matching B-side bijection; o2 = row-sums via ones column
    f32x4 o0 = (f32x4){0.f, 0.f, 0.f, 0.f};
    f32x4 o1 = (f32x4){0.f, 0.f, 0.f, 0.f};
    f32x4 o2 = (f32x4){0.f, 0.f, 0.f, 0.f};
#pragma unroll
    for (int nf2 = 0; nf2 < 8; ++nf2) {
        bf16x4 lo0 = *(const bf16x4*)(Vt + lrow * 264 + nf2 * 32 + lkg * 4);
        bf16x4 hi0 = *(const bf16x4*)(Vt + lrow * 264 + nf2 * 32 + 16 + lkg * 4);
        bf16x4 lo1 = *(const bf16x4*)(Vt + (16 + lrow) * 264 + nf2 * 32 + lkg * 4);
        bf16x4 hi1 = *(const bf16x4*)(Vt + (16 + lrow) * 264 + nf2 * 32 + 16 + lkg * 4);
        bf16x8 v0 = __builtin_shufflevector(lo0, hi0, 0, 1, 2, 3, 4, 5, 6, 7);
        bf16x8 v1 = __builtin_shufflevector(lo1, hi1, 0, 1, 2, 3, 4, 5, 6, 7);
        o0 = __builtin_amdgcn_mfma_f32_16x16x32_bf16(pa8[nf2], v0, o0, 0, 0, 0);
        o1 = __builtin_amdgcn_mfma_f32_16x16x32_bf16(pa8[nf2], v1, o1, 0, 0, 0);
        o2 = __builtin_amdgcn_mfma_f32_16x16x32_bf16(pa8[nf2], onesf, o2, 0, 0, 0);
    }

    // 1/rowsum: sums live in lanes lrow==0 (rows lkg*4+r); broadcast within each lkg group
    float invq[4];
#pragma unroll
    for (int r = 0; r < 4; ++r)
        invq[r] = __shfl(__builtin_amdgcn_rcpf(o2[r]), lane & 48);

    const size_t obase = (size_t)(b * 4096 + qt * 64 + wid * 16);
#pragma unroll
    for (int r = 0; r < 4; ++r) {
        u16* op = obuf + (obase + lkg * 4 + r) * 256 + h * 32 + lrow;
        op[0]  = f2bf(o0[r] * invq[r]);
        op[16] = f2bf(o1[r] * invq[r]);
    }
}

extern "C" void kernel_launch(void* const* d_in, const int* in_sizes, int n_in,
                              void* d_out, int out_size, void* d_ws, size_t ws_size,
                              hipStream_t stream)
{
    (void)in_sizes; (void)n_in; (void)out_size; (void)ws_size;
    const float* x   = (const float*)d_in[0];
    const float* qw  = (const float*)d_in[3];
    const float* qb  = (const float*)d_in[4];
    const float* kvw = (const float*)d_in[5];
    const float* kvb = (const float*)d_in[6];
    const float* srw = (const float*)d_in[7];
    const float* srb = (const float*)d_in[8];
    const float* lng = (const float*)d_in[9];
    const float* lnb = (const float*)d_in[10];
    const float* pw  = (const float*)d_in[11];
    const float* pb  = (const float*)d_in[12];

    char* ws = (char*)d_ws;
    u16*   xb      = (u16*)(ws + 0);          // 16.78 MB  x as bf16 [32768][256]
    u16*   att     = (u16*)(ws + 16777216);   // 16.78 MB  attention output bf16 [32768][256]
    float* part    = (float*)(ws + 33554432); //  8.39 MB  conv split-K partials [4][2048][256]
    u16*   wsr     = (u16*)(ws + 50331648);   //  2.10 MB
    u16*   wqb     = (u16*)(ws + 52428800);
    u16*   wkvb    = (u16*)(ws + 52559872);
    u16*   wpb     = (u16*)(ws + 52822016);
    u16*   xsr     = (u16*)(ws + 52953088);   //  1.05 MB  LN output bf16 [2048][256]
    u16*   kvo     = (u16*)(ws + 54001664);   //  2.10 MB  kv bf16 [2048][512] (k pre-scaled)
    u16*   qbuf    = (u16*)d_out;             // q bf16 [32768][256] in d_out scratch (overwritten by proj)

    prep_all<<<8192, 256, 0, stream>>>(x, xb, qw, kvw, pw, srw, wqb, wkvb, wpb, wsr);
    // conv (split-K x4, im2col-on-the-fly) + q projection fused into one 640-block launch
    fused_convq<<<640, 256, 0, stream>>>(xb, wsr, part, wqb, qb, qbuf);
    ln_kernel<<<2048, 256, 0, stream>>>(part, srb, lng, lnb, xsr);
    gemm128<1, true,  false><<<dim3(16, 4, 1), 256, 0, stream>>>(xsr, wkvb, kvb, kvo, 2048, 512, 256, 256);
    attn_kernel<<<dim3(64, 8, 8), 256, 0, stream>>>(qbuf, kvo, att);
    gemm128<0, false, false><<<dim3(256, 2, 1), 256, 0, stream>>>(att, wpb, pb, d_out, 32768, 256, 256, 256);
}

// Round 11
// 94.064 us; speedup vs baseline: 1.3509x; 1.0123x over previous
//
#include <hip/hip_runtime.h>

typedef unsigned short u16;
typedef float f32x4 __attribute__((ext_vector_type(4)));
typedef __bf16 bf16x4 __attribute__((ext_vector_type(4)));
typedef __bf16 bf16x8 __attribute__((ext_vector_type(8)));

#define B_ 8
#define N_ 4096
#define C_ 256
#define NKV 256
// softmax scale folded into k: 1/sqrt(32) * log2(e)
#define CEXP 0.25506604f

__device__ inline u16 f2bf(float f) {
    union { float f; unsigned u; } v; v.f = f;
    unsigned r = v.u + 0x7FFF + ((v.u >> 16) & 1);
    return (u16)(r >> 16);
}

// async global->LDS, 16B per lane (dest must be wave-linear: base + lane*16)
__device__ inline void gload16(const void* g, void* l) {
    __builtin_amdgcn_global_load_lds(
        (const __attribute__((address_space(1))) void*)g,
        (__attribute__((address_space(3))) void*)l, 16, 0, 0);
}

// ---------------- prep (merged): x -> bf16 xb; weights -> bf16 ----------------
__global__ __launch_bounds__(256) void prep_all(
    const float* __restrict__ x, u16* __restrict__ xb,
    const float* __restrict__ qw, const float* __restrict__ kvw,
    const float* __restrict__ pw, const float* __restrict__ srw,
    u16* __restrict__ wqb, u16* __restrict__ wkv, u16* __restrict__ wp, u16* __restrict__ wsr)
{
    // x part: one float4 per thread over 8192x256 threads (no im2col buffer:
    // the conv GEMM stages its A-tile straight from xb with im2col addressing)
    size_t base = ((size_t)blockIdx.x * 256 + threadIdx.x) * 4;
    float4 v = *(const float4*)(x + base);
    ushort4 o;
    o.x = f2bf(v.x); o.y = f2bf(v.y); o.z = f2bf(v.z); o.w = f2bf(v.w);
    *(ushort4*)(xb + base) = o;

    // weight part (strided over the whole grid)
    int t = blockIdx.x * 256 + threadIdx.x;
    int stride = gridDim.x * 256;
    for (int i = t; i < 65536; i += stride) { wqb[i] = f2bf(qw[i]); wp[i] = f2bf(pw[i]); }
    for (int i = t; i < 131072; i += stride) wkv[i] = f2bf(kvw[i]);
    // wsr[o][(kh*4+kw)*256 + ci] = srw[o][ci][kh][kw]
    for (int i = t; i < 1048576; i += stride) {
        int oo = i >> 12, kk = i & 4095;
        int ci = kk & 255, khkw = kk >> 8;
        wsr[i] = f2bf(srw[(size_t)(oo * 256 + ci) * 16 + khkw]);
    }
}

// ---------------- 128x128 bf16 MFMA GEMM body with global_load_lds staging ----------------
// out = A[M,K] @ Bt[N,K]^T (+bias). LDS tiles [128][32] UNPADDED (global_load_lds requires
// linear lane->dest); fragment-read bank conflicts accepted (m97 pattern).
// OUTMODE: 0 = f32 out + bias, 1 = bf16 out + bias, 2 = f32 split-K partial (no bias)
// SCALEK: multiply cols < 256 by CEXP (softmax scale fold for the kv projection's k half)
// IM2COL: A is xb [B*N][C]; logical A-row = b*256 + hp*16 + wp, k = (kh*4+kw)*256 + c.
template<int OUTMODE, bool SCALEK, bool IM2COL>
__device__ __forceinline__ void gemm_body(
    u16* As, u16* Bs,
    const u16* __restrict__ A, const u16* __restrict__ Bt,
    const float* __restrict__ bias, void* __restrict__ outp,
    int M, int Nn, int K, int kchunk, int bm, int bn, int bz)
{
    const int tid = threadIdx.x;
    const int k0 = bz * kchunk;
    const int wid = tid >> 6, lane = tid & 63;
    const int wr = wid >> 1, wc = wid & 1;
    const int lrow = lane & 15, lkg = lane >> 4;

    f32x4 acc[4][4] = {};

    // staging: chunk c covers row c>>2, 16B-piece c&3 (linear in LDS)
    const int c1 = tid, c2 = tid + 256;
    const int r1 = c1 >> 2, cl1 = (c1 & 3) * 8;
    const int r2 = c2 >> 2, cl2 = (c2 & 3) * 8;
    const u16 *aS1, *aS2;
    if constexpr (IM2COL) {
        const int g1 = bm * 128 + r1, g2 = bm * 128 + r2;
        const int b1 = g1 >> 8, p1 = g1 & 255;
        const int b2 = g2 >> 8, p2 = g2 & 255;
        aS1 = A + ((size_t)(b1 * 4096 + (p1 >> 4) * 256 + (p1 & 15) * 4) * 256 + cl1);
        aS2 = A + ((size_t)(b2 * 4096 + (p2 >> 4) * 256 + (p2 & 15) * 4) * 256 + cl2);
    } else {
        aS1 = A + (size_t)(bm * 128 + r1) * K + k0 + cl1;
        aS2 = A + (size_t)(bm * 128 + r2) * K + k0 + cl2;
    }
    const u16* bS1 = Bt + (size_t)(bn * 128 + r1) * K + k0 + cl1;
    const u16* bS2 = Bt + (size_t)(bn * 128 + r2) * K + k0 + cl2;
    u16* aD1 = As + c1 * 8;  u16* aD2 = As + c2 * 8;
    u16* bD1 = Bs + c1 * 8;  u16* bD2 = Bs + c2 * 8;

    for (int kk = 0; kk < kchunk; kk += 32) {
        int aoff;
        if constexpr (IM2COL) {
            const int K0 = k0 + kk;
            const int khkw = K0 >> 8;
            aoff = ((khkw >> 2) * 64 + (khkw & 3)) * 256 + (K0 & 255);
        } else {
            aoff = kk;
        }
        gload16(aS1 + aoff, aD1);
        gload16(aS2 + aoff, aD2);
        gload16(bS1 + kk, bD1);
        gload16(bS2 + kk, bD2);
        __syncthreads();   // compiler drains vmcnt before s_barrier
        bf16x8 af[4], bff[4];
#pragma unroll
        for (int i = 0; i < 4; ++i) {
            af[i]  = *(const bf16x8*)(As + (wr * 64 + i * 16 + lrow) * 32 + lkg * 8);
            bff[i] = *(const bf16x8*)(Bs + (wc * 64 + i * 16 + lrow) * 32 + lkg * 8);
        }
#pragma unroll
        for (int i = 0; i < 4; ++i)
#pragma unroll
            for (int j = 0; j < 4; ++j)
                acc[i][j] = __builtin_amdgcn_mfma_f32_16x16x32_bf16(af[i], bff[j], acc[i][j], 0, 0, 0);
        __syncthreads();
    }

    const int row0 = bm * 128 + wr * 64;
    const int col0 = bn * 128 + wc * 64;
    if constexpr (OUTMODE == 2) {
        float* o = (float*)outp + (size_t)bz * M * Nn;
#pragma unroll
        for (int i = 0; i < 4; ++i)
#pragma unroll
            for (int j = 0; j < 4; ++j)
#pragma unroll
                for (int reg = 0; reg < 4; ++reg)
                    o[(size_t)(row0 + i * 16 + lkg * 4 + reg) * Nn + col0 + j * 16 + lrow] = acc[i][j][reg];
    } else {
#pragma unroll
        for (int j = 0; j < 4; ++j) {
            const int col = col0 + j * 16 + lrow;
            float bv = bias[col];
            float sc = 1.0f;
            if constexpr (SCALEK) { if (col < 256) sc = CEXP; }
#pragma unroll
            for (int i = 0; i < 4; ++i)
#pragma unroll
                for (int reg = 0; reg < 4; ++reg) {
                    const size_t idx = (size_t)(row0 + i * 16 + lkg * 4 + reg) * Nn + col;
                    const float val = (acc[i][j][reg] + bv) * sc;
                    if constexpr (OUTMODE == 1) ((u16*)outp)[idx] = f2bf(val);
                    else                        ((float*)outp)[idx] = val;
                }
        }
    }
}

// standalone GEMM wrapper (kv projection, output projection)
template<int OUTMODE, bool SCALEK, bool IM2COL>
__global__ __launch_bounds__(256, 2) void gemm128(
    const u16* __restrict__ A, const u16* __restrict__ Bt,
    const float* __restrict__ bias, void* __restrict__ outp,
    int M, int Nn, int K, int kchunk)
{
    __shared__ __align__(16) u16 As[128 * 32];
    __shared__ __align__(16) u16 Bs[128 * 32];
    gemm_body<OUTMODE, SCALEK, IM2COL>(As, Bs, A, Bt, bias, outp, M, Nn, K, kchunk,
                                       blockIdx.x, blockIdx.y, blockIdx.z);
}

// ---------------- fused launch: conv GEMM (split-K x4, im2col) + q projection -------------
// ids 0..127: conv (16 bm x 2 bn x 4 z, K=1024 each) — long poles dispatched first.
// ids 128..639: q proj (256 bm x 2 bn, K=256). Independent work fills remaining CUs.
__global__ __launch_bounds__(256, 2) void fused_convq(
    const u16* __restrict__ xb, const u16* __restrict__ wsr, float* __restrict__ part,
    const u16* __restrict__ wqb, const float* __restrict__ qb, u16* __restrict__ qbuf)
{
    __shared__ __align__(16) u16 As[128 * 32];
    __shared__ __align__(16) u16 Bs[128 * 32];
    const int id = blockIdx.x;
    if (id < 128) {
        const int z = id & 3, t = id >> 2;
        gemm_body<2, false, true>(As, Bs, xb, wsr, nullptr, part,
                                  2048, 256, 4096, 1024, t >> 1, t & 1, z);
    } else {
        const int qid = id - 128;
        gemm_body<1, false, false>(As, Bs, xb, wqb, qb, qbuf,
                                   32768, 256, 256, 256, qid >> 1, qid & 1, 0);
    }
}

// ---------------- LN over conv partial sums: xsr = LN(sum_z part + sr_b) -> bf16 ----------------
__global__ __launch_bounds__(256) void ln_kernel(
    const float* __restrict__ part, const float* __restrict__ srb,
    const float* __restrict__ g, const float* __restrict__ bb, u16* __restrict__ out)
{
    const int row = blockIdx.x, c = threadIdx.x;
    const size_t idx = (size_t)row * 256 + c;
    float v = srb[c];
#pragma unroll
    for (int z = 0; z < 4; ++z) v += part[idx + (size_t)z * 524288];
    float s = v;
#pragma unroll
    for (int m = 1; m < 64; m <<= 1) s += __shfl_xor(s, m);
    __shared__ float red[4];
    if ((c & 63) == 0) red[c >> 6] = s;
    __syncthreads();
    float tot = red[0] + red[1] + red[2] + red[3];
    float mu = tot * (1.0f / 256.0f);
    float d = v - mu;
    float s2 = d * d;
#pragma unroll
    for (int m = 1; m < 64; m <<= 1) s2 += __shfl_xor(s2, m);
    __syncthreads();
    if ((c & 63) == 0) red[c >> 6] = s2;
    __syncthreads();
    float var = (red[0] + red[1] + red[2] + red[3]) * (1.0f / 256.0f);
    out[idx] = f2bf(d * rsqrtf(var + 1e-5f) * g[c] + bb[c]);
}

// ---------------- fused attention (v7 structure; occupancy-tuned) -------------------------
// Per block: (b, h, 64 q-rows); grid 4096 blocks. K[256][32] linear (async gload_lds) +
// V^T[32][264] in LDS (33.3 KB). __launch_bounds__(256,4): live state ~110 VGPR fits the
// 128 cap -> 4 blocks/CU, doubling cross-wave overlap of the exp2 VALU phase with MFMA.
// V^T staged as packed b32 writes (16/thread vs 32 scalar u16). k pre-scaled by CEXP in the
// kv GEMM; softmax is max-free (scores tiny). S^T layout = 16x16x32 A-fragment under the
// shared k-bijection slot(lkg,e) = (e<4 ? lkg*4+e : 16+lkg*4+e-4). Row-sums via ones-MFMA.
__global__ __launch_bounds__(256, 4) void attn_kernel(
    const u16* __restrict__ qbuf, const u16* __restrict__ kvbuf, u16* __restrict__ obuf)
{
    __shared__ __align__(16) u16 Ks[256 * 32];   // 16384 B (linear: row r at r*32)
    __shared__ __align__(16) u16 Vt[32 * 264];   // 16896 B  Vt[d][k]
    const int qt = blockIdx.x, h = blockIdx.y, b = blockIdx.z;
    const int tid = threadIdx.x;
    const int wid = tid >> 6, lane = tid & 63;
    const int lrow = lane & 15, lkg = lane >> 4;

    // stage K via async global->LDS: call c (= wid*4+i) covers rows [c*16, c*16+16)
    {
        const int rsub = lane >> 2, piece = lane & 3;
#pragma unroll
        for (int i = 0; i < 4; ++i) {
            const int c = wid * 4 + i;
            const u16* src = kvbuf + (size_t)(b * 256 + c * 16 + rsub) * 512 + h * 32 + piece * 8;
            gload16(src, Ks + c * 512 + lane * 8);
        }
    }
    // stage V^T packed: thread t covers v-rows 2i,2i+1 (i=t&127), d-slice (t>>7)*16..+16;
    // writes 16 b32 words (v[2i+1][d]<<16 | v[2i][d]) at Vt[d][2i] — halves write count.
    {
        const int i = tid & 127, dbase = (tid >> 7) * 16;
        const u16* vs0 = kvbuf + (size_t)(b * 256 + 2 * i) * 512 + 256 + h * 32 + dbase;
        const u16* vs1 = vs0 + 512;
        ushort4 a0 = *(const ushort4*)(vs0);
        ushort4 a1 = *(const ushort4*)(vs0 + 4);
        ushort4 a2 = *(const ushort4*)(vs0 + 8);
        ushort4 a3 = *(const ushort4*)(vs0 + 12);
        ushort4 b0 = *(const ushort4*)(vs1);
        ushort4 b1 = *(const ushort4*)(vs1 + 4);
        ushort4 b2 = *(const ushort4*)(vs1 + 8);
        ushort4 b3 = *(const ushort4*)(vs1 + 12);
        unsigned* vw = (unsigned*)(Vt + (size_t)dbase * 264 + 2 * i);
#define VPACK(d, lo, hi) vw[(d) * 132] = ((unsigned)(hi) << 16) | (lo)
        VPACK(0,  a0.x, b0.x); VPACK(1,  a0.y, b0.y); VPACK(2,  a0.z, b0.z); VPACK(3,  a0.w, b0.w);
        VPACK(4,  a1.x, b1.x); VPACK(5,  a1.y, b1.y); VPACK(6,  a1.z, b1.z); VPACK(7,  a1.w, b1.w);
        VPACK(8,  a2.x, b2.x); VPACK(9,  a2.y, b2.y); VPACK(10, a2.z, b2.z); VPACK(11, a2.w, b2.w);
        VPACK(12, a3.x, b3.x); VPACK(13, a3.y, b3.y); VPACK(14, a3.z, b3.z); VPACK(15, a3.w, b3.w);
#undef VPACK
    }

    // Q B-fragment straight from global (16B/lane)
    const int qcol = h * 32 + lkg * 8;
    bf16x8 qf = *(const bf16x8*)(qbuf +
        (size_t)(b * 4096 + qt * 64 + wid * 16 + lrow) * 256 + qcol);

    // ones B-fragment for the row-sum MFMA (col-of-tile 0 only)
    bf16x8 onesf = {};
    if (lrow == 0) {
#pragma unroll
        for (int e = 0; e < 8; ++e) onesf[e] = (__bf16)1.0f;
    }

    __syncthreads();

    // S^T = K @ Q^T (scores pre-scaled by CEXP via the kv GEMM)
    f32x4 acc[16];
#pragma unroll
    for (int nf = 0; nf < 16; ++nf) acc[nf] = (f32x4){0.f, 0.f, 0.f, 0.f};
#pragma unroll
    for (int nf = 0; nf < 16; ++nf) {
        bf16x8 kfr = *(const bf16x8*)(Ks + (nf * 16 + lrow) * 32 + lkg * 8);
        acc[nf] = __builtin_amdgcn_mfma_f32_16x16x32_bf16(kfr, qf, acc[nf], 0, 0, 0);
    }

    // max-free softmax numerator: exp2 directly, fused bf16 pack
    bf16x8 pa8[8];
#pragma unroll
    for (int nf2 = 0; nf2 < 8; ++nf2) {
        bf16x8 pv;
#pragma unroll
        for (int half = 0; half < 2; ++half) {
#pragma unroll
            for (int r = 0; r < 4; ++r)
                pv[half * 4 + r] = (__bf16)exp2f(acc[2 * nf2 + half][r]);
        }
        pa8[nf2] = pv;
    }

    // O = P @ V via 16x16x32 with matching B-side bijection; o2 = row-sums via ones column
    f32x4 o0 = (f32x4){0.f, 0.f, 0.f, 0.f};
    f32x4 o1 = (f32x4){0.f, 0.f, 0.f, 0.f};
    f32x4 o2 = (f32x4){0.f, 0.f, 0.f, 0.f};
#pragma unroll
    for (int nf2 = 0; nf2 < 8; ++nf2) {
        bf16x4 lo0 = *(const bf16x4*)(Vt + lrow * 264 + nf2 * 32 + lkg * 4);
        bf16x4 hi0 = *(const bf16x4*)(Vt + lrow * 264 + nf2 * 32 + 16 + lkg * 4);
        bf16x4 lo1 = *(const bf16x4*)(Vt + (16 + lrow) * 264 + nf2 * 32 + lkg * 4);
        bf16x4 hi1 = *(const bf16x4*)(Vt + (16 + lrow) * 264 + nf2 * 32 + 16 + lkg * 4);
        bf16x8 v0 = __builtin_shufflevector(lo0, hi0, 0, 1, 2, 3, 4, 5, 6, 7);
        bf16x8 v1 = __builtin_shufflevector(lo1, hi1, 0, 1, 2, 3, 4, 5, 6, 7);
        o0 = __builtin_amdgcn_mfma_f32_16x16x32_bf16(pa8[nf2], v0, o0, 0, 0, 0);
        o1 = __builtin_amdgcn_mfma_f32_16x16x32_bf16(pa8[nf2], v1, o1, 0, 0, 0);
        o2 = __builtin_amdgcn_mfma_f32_16x16x32_bf16(pa8[nf2], onesf, o2, 0, 0, 0);
    }

    // 1/rowsum: sums live in lanes lrow==0 (rows lkg*4+r); broadcast within each lkg group
    float invq[4];
#pragma unroll
    for (int r = 0; r < 4; ++r)
        invq[r] = __shfl(__builtin_amdgcn_rcpf(o2[r]), lane & 48);

    const size_t obase = (size_t)(b * 4096 + qt * 64 + wid * 16);
#pragma unroll
    for (int r = 0; r < 4; ++r) {
        u16* op = obuf + (obase + lkg * 4 + r) * 256 + h * 32 + lrow;
        op[0]  = f2bf(o0[r] * invq[r]);
        op[16] = f2bf(o1[r] * invq[r]);
    }
}

extern "C" void kernel_launch(void* const* d_in, const int* in_sizes, int n_in,
                              void* d_out, int out_size, void* d_ws, size_t ws_size,
                              hipStream_t stream)
{
    (void)in_sizes; (void)n_in; (void)out_size; (void)ws_size;
    const float* x   = (const float*)d_in[0];
    const float* qw  = (const float*)d_in[3];
    const float* qb  = (const float*)d_in[4];
    const float* kvw = (const float*)d_in[5];
    const float* kvb = (const float*)d_in[6];
    const float* srw = (const float*)d_in[7];
    const float* srb = (const float*)d_in[8];
    const float* lng = (const float*)d_in[9];
    const float* lnb = (const float*)d_in[10];
    const float* pw  = (const float*)d_in[11];
    const float* pb  = (const float*)d_in[12];

    char* ws = (char*)d_ws;
    u16*   xb      = (u16*)(ws + 0);          // 16.78 MB  x as bf16 [32768][256]
    u16*   att     = (u16*)(ws + 16777216);   // 16.78 MB  attention output bf16 [32768][256]
    float* part    = (float*)(ws + 33554432); //  8.39 MB  conv split-K partials [4][2048][256]
    u16*   wsr     = (u16*)(ws + 50331648);   //  2.10 MB
    u16*   wqb     = (u16*)(ws + 52428800);
    u16*   wkvb    = (u16*)(ws + 52559872);
    u16*   wpb     = (u16*)(ws + 52822016);
    u16*   xsr     = (u16*)(ws + 52953088);   //  1.05 MB  LN output bf16 [2048][256]
    u16*   kvo     = (u16*)(ws + 54001664);   //  2.10 MB  kv bf16 [2048][512] (k pre-scaled)
    u16*   qbuf    = (u16*)d_out;             // q bf16 [32768][256] in d_out scratch (overwritten by proj)

    prep_all<<<8192, 256, 0, stream>>>(x, xb, qw, kvw, pw, srw, wqb, wkvb, wpb, wsr);
    // conv (split-K x4, im2col-on-the-fly) + q projection fused into one 640-block launch
    fused_convq<<<640, 256, 0, stream>>>(xb, wsr, part, wqb, qb, qbuf);
    ln_kernel<<<2048, 256, 0, stream>>>(part, srb, lng, lnb, xsr);
    gemm128<1, true,  false><<<dim3(16, 4, 1), 256, 0, stream>>>(xsr, wkvb, kvb, kvo, 2048, 512, 256, 256);
    attn_kernel<<<dim3(64, 8, 8), 256, 0, stream>>>(qbuf, kvo, att);
    gemm128<0, false, false><<<dim3(256, 2, 1), 256, 0, stream>>>(att, wpb, pb, d_out, 32768, 256, 256, 256);
}